// Round 7
// baseline (154.142 us; speedup 1.0000x reference)
//
#include <hip/hip_runtime.h>

// SymmetryControl: B=16, C=96, H=96, W=96 fp32.
// out[b,c,h,i] = num/den, 6 taps of the same 96-wide row, gated by sigmoid(s[b,:]).
//
// R11 theory: R1-R10 all sit at 2.0-2.3 TB/s. No round achieved BOTH high
// occupancy AND proven per-wave pipeline depth (R9: depth at 20% occ; R10:
// 60% occ but VGPR=32 < the 35 needed for a live 4-batch -> depth collapsed).
// Little's law: ~1-2KB/wave x ~18 waves/CU / ~900cyc = 2.2 TB/s = the wall.
// R11 forces both: (a) persistent grid 2048 blocks x 4 waves = exactly 8
// blocks/CU = 32 waves/CU, one-shot, no turnover; (b) per wave, 9 row-pairs
// through a 3-slot rolling pipeline where EVERY VMEM op (loads AND stores) is
// volatile inline asm, so the in-order vmcnt arithmetic is exact:
//   issue order: L0 L1 | L2 w C0 S0 | L3 w C1 S1 | ... | L(t+2) w Ct St | ...
//   wait before Ct needs L(t) retired; younger ops = S(t-2),L(t+1),S(t-1),L(t+2)
//   = 12 -> s_waitcnt vmcnt(12) steady state (t0:8, t1:10, t7:8, t8:4).
// Stores never block; no vmcnt(0) mid-loop. Gate computation is fenced ABOVE
// the first asm load (sched_barrier) so the compiler's own waitcnt for the s[]
// loads can't inject vmcnt(0) into the pipeline. Steady state: ~4.5 KB in
// flight/wave x 32 waves/CU ~= 140 KB/CU outstanding (~100x R1-R8).
//
// Row->lane map (verified R6/R7/R10): row = 32 lanes x 3 floats, 2 rows/wave:
//   col i = 3*tl + e
//   shift -24: lane (tl-8)&31,  same elem
//   shift -48: lane (tl-16)&31, same elem
//   shift -72: lane (tl+8)&31,  same elem
//   flip 23-i: lane (7-tl)&31,  elems reversed
//   flip 47-i: lane (15-tl)&31, elems reversed

#define WDIM 96
#define WPB  4               // waves per block (256 threads)
#define NP   9               // row-pairs per wave (18 rows)
#define GRID 2048            // 8 blocks/CU exactly; 2048*4*18 = 147456 rows

typedef float v2f __attribute__((ext_vector_type(2)));

__device__ __forceinline__ float bperm(int byteidx, float v) {
    return __int_as_float(__builtin_amdgcn_ds_bpermute(byteidx, __float_as_int(v)));
}

__global__ __launch_bounds__(64 * WPB)
void symctl_kernel(const float* __restrict__ x,
                   const float* __restrict__ s,
                   const float* __restrict__ w,
                   float* __restrict__ out) {
    const int lane = threadIdx.x & 63;
    const int tl   = lane & 31;          // position within 32-lane half
    const int hsel = lane & 32;          // half selector (0 / 32)
    const int h    = lane >> 5;          // row parity within each pair

    const int gw   = blockIdx.x * WPB + (threadIdx.x >> 6);   // global wave id
    // wave owns rows [18*gw, 18*gw+18); lane covers rows 18*gw + 2k + h
    const int voff = ((18 * gw + h) * WDIM + 3 * tl) * 4;     // byte offset, <2^31

    // ---- gates FIRST (their loads + compiler vmcnt bookkeeping fully retire
    //      before any asm load issues; fence below pins them above) ----
    const int b = blockIdx.x >> 7;       // 2048 blocks / 16 batches = 128
    const float* sb = s + b * 5;
    const float sg0 = 1.0f / (1.0f + __expf(-sb[0]));
    const float sg1 = 1.0f / (1.0f + __expf(-sb[1]));
    const float sg2 = 1.0f / (1.0f + __expf(-sb[2]));
    const float sg3 = 1.0f / (1.0f + __expf(-sb[3]));
    const float sg4 = 1.0f / (1.0f + __expf(-sb[4]));

    // bpermute byte indices (per-lane constants, stay within own 32-lane half)
    const int i90  = (hsel | ((tl -  8) & 31)) << 2;
    const int i180 = (hsel | ((tl - 16) & 31)) << 2;
    const int i270 = (hsel | ((tl +  8) & 31)) << 2;
    const int f90  = (hsel | (( 7 - tl) & 31)) << 2;
    const int f180 = (hsel | ((15 - tl) & 31)) << 2;

    __builtin_amdgcn_sched_barrier(0);   // nothing above (incl. gate loads) may sink below

    // 3 rolling slots (A: pairs 0,3,6; B: 1,4,7; C: 2,5,8)
    v2f   xloA, xloB, xloC, wloA, wloB, wloC;
    float xhiA, xhiB, xhiC, whiA, whiB, whiC;

#define LD(K, XLO, XHI, WLO, WHI)                                               \
    {                                                                           \
        const int a_ = voff + (K) * 768;                                        \
        asm volatile("global_load_dwordx2 %0, %1, %2"                           \
                     : "=v"(XLO) : "v"(a_), "s"(x));                            \
        asm volatile("global_load_dword %0, %1, %2 offset:8"                    \
                     : "=v"(XHI) : "v"(a_), "s"(x));                            \
        asm volatile("global_load_dwordx2 %0, %1, %2"                           \
                     : "=v"(WLO) : "v"(a_), "s"(w));                            \
        asm volatile("global_load_dword %0, %1, %2 offset:8"                    \
                     : "=v"(WHI) : "v"(a_), "s"(w));                            \
    }

#define WAITN(N)                                                                \
    asm volatile("s_waitcnt vmcnt(" #N ")" ::: "memory");                       \
    __builtin_amdgcn_sched_barrier(0);

#define CST(K, XLO, XHI, WLO, WHI)                                              \
    {                                                                           \
        const float wcx = WLO.x, wcy = WLO.y, wcz = WHI;                        \
        const float p0 = XLO.x * wcx;                                           \
        const float p1 = XLO.y * wcy;                                           \
        const float p2 = XHI   * wcz;                                           \
        float n0 = p0, n1 = p1, n2 = p2;                                        \
        float d0 = wcx, d1 = wcy, d2 = wcz;                                     \
        n0 = fmaf(sg0, bperm(i90,  p0),  n0);                                   \
        n1 = fmaf(sg0, bperm(i90,  p1),  n1);                                   \
        n2 = fmaf(sg0, bperm(i90,  p2),  n2);                                   \
        d0 = fmaf(sg0, bperm(i90,  wcx), d0);                                   \
        d1 = fmaf(sg0, bperm(i90,  wcy), d1);                                   \
        d2 = fmaf(sg0, bperm(i90,  wcz), d2);                                   \
        n0 = fmaf(sg1, bperm(i180, p0),  n0);                                   \
        n1 = fmaf(sg1, bperm(i180, p1),  n1);                                   \
        n2 = fmaf(sg1, bperm(i180, p2),  n2);                                   \
        d0 = fmaf(sg1, bperm(i180, wcx), d0);                                   \
        d1 = fmaf(sg1, bperm(i180, wcy), d1);                                   \
        d2 = fmaf(sg1, bperm(i180, wcz), d2);                                   \
        n0 = fmaf(sg2, bperm(i270, p0),  n0);                                   \
        n1 = fmaf(sg2, bperm(i270, p1),  n1);                                   \
        n2 = fmaf(sg2, bperm(i270, p2),  n2);                                   \
        d0 = fmaf(sg2, bperm(i270, wcx), d0);                                   \
        d1 = fmaf(sg2, bperm(i270, wcy), d1);                                   \
        d2 = fmaf(sg2, bperm(i270, wcz), d2);                                   \
        n0 = fmaf(sg3, bperm(f90,  p2),  n0);                                   \
        n1 = fmaf(sg3, bperm(f90,  p1),  n1);                                   \
        n2 = fmaf(sg3, bperm(f90,  p0),  n2);                                   \
        d0 = fmaf(sg3, bperm(f90,  wcz), d0);                                   \
        d1 = fmaf(sg3, bperm(f90,  wcy), d1);                                   \
        d2 = fmaf(sg3, bperm(f90,  wcx), d2);                                   \
        n0 = fmaf(sg4, bperm(f180, p2),  n0);                                   \
        n1 = fmaf(sg4, bperm(f180, p1),  n1);                                   \
        n2 = fmaf(sg4, bperm(f180, p0),  n2);                                   \
        d0 = fmaf(sg4, bperm(f180, wcz), d0);                                   \
        d1 = fmaf(sg4, bperm(f180, wcy), d1);                                   \
        d2 = fmaf(sg4, bperm(f180, wcx), d2);                                   \
        v2f olo;                                                                \
        olo.x = n0 * __builtin_amdgcn_rcpf(d0);                                 \
        olo.y = n1 * __builtin_amdgcn_rcpf(d1);                                 \
        const float ohi = n2 * __builtin_amdgcn_rcpf(d2);                       \
        const int a_ = voff + (K) * 768;                                        \
        asm volatile("global_store_dwordx2 %0, %1, %2"                          \
                     :: "v"(a_), "v"(olo), "s"(out) : "memory");                \
        asm volatile("global_store_dword %0, %1, %2 offset:8"                   \
                     :: "v"(a_), "v"(ohi), "s"(out) : "memory");                \
    }

    // ---- prologue: pairs 0,1 in flight ----
    LD(0, xloA, xhiA, wloA, whiA)
    LD(1, xloB, xhiB, wloB, whiB)

    // ---- rolling pipeline, fully static (slots and waits hardcoded) ----
    LD(2, xloC, xhiC, wloC, whiC)  WAITN(8)   CST(0, xloA, xhiA, wloA, whiA)
    LD(3, xloA, xhiA, wloA, whiA)  WAITN(10)  CST(1, xloB, xhiB, wloB, whiB)
    LD(4, xloB, xhiB, wloB, whiB)  WAITN(12)  CST(2, xloC, xhiC, wloC, whiC)
    LD(5, xloC, xhiC, wloC, whiC)  WAITN(12)  CST(3, xloA, xhiA, wloA, whiA)
    LD(6, xloA, xhiA, wloA, whiA)  WAITN(12)  CST(4, xloB, xhiB, wloB, whiB)
    LD(7, xloB, xhiB, wloB, whiB)  WAITN(12)  CST(5, xloC, xhiC, wloC, whiC)
    LD(8, xloC, xhiC, wloC, whiC)  WAITN(12)  CST(6, xloA, xhiA, wloA, whiA)
                                   WAITN(8)   CST(7, xloB, xhiB, wloB, whiB)
                                   WAITN(4)   CST(8, xloC, xhiC, wloC, whiC)

#undef LD
#undef WAITN
#undef CST
}

extern "C" void kernel_launch(void* const* d_in, const int* in_sizes, int n_in,
                              void* d_out, int out_size, void* d_ws, size_t ws_size,
                              hipStream_t stream) {
    const float* x = (const float*)d_in[0];
    const float* s = (const float*)d_in[1];
    const float* w = (const float*)d_in[2];
    float* out = (float*)d_out;

    // 2048 blocks x 4 waves x 18 rows = 147456 rows (exact for the fixed shape)
    dim3 block(64 * WPB);
    symctl_kernel<<<GRID, block, 0, stream>>>(x, s, w, out);
}

// Round 9
// 152.667 us; speedup vs baseline: 1.0097x; 1.0097x over previous
//
#include <hip/hip_runtime.h>

// SymmetryControl: B=16, C=96, H=96, W=96 fp32.
// out[b,c,h,i] = num/den, 6 taps of the same 96-wide row, gated by sigmoid(s[b,:]).
//
// R13 = R12 resubmit (R12 bench died in infra: "container failed twice", no
// compile/correctness signal — the experiment never ran).
//
// Theory under test: R11 proved a live 3-deep per-wave pipeline (VGPR=24 =
// 18 slot regs + 5 idx + voff, asm-volatile order, hand-counted vmcnt) at 45%+
// occupancy and perf STILL sat at 52 us / 2.2 TB/s => service-rate-limited,
// not latency-exposed. Counters point at one untested mechanism: FETCH=55MB vs
// 113MB of reads — half the reads are Infinity Cache hits. If the IC-hit/HBM
// blend services reads slower than pure streaming, the blend is the throttle
// and every structure plateaus identically (exactly R1-R11). Single-variable
// test: `nt` (no-allocate/evict-first) on every VMEM op.
// Engage check: FETCH 55 -> >=90MB. Outcomes pre-committed:
//   dur -> 32-40us: IC-path confirmed, iterate further.
//   FETCH up, dur flat: upstream request-path ceiling -> ROOFLINE next round.
//   FETCH flat: nt ignored on this path -> ROOFLINE next round.
//
// Row->lane map (verified R6/R7/R10/R11): row = 32 lanes x 3 floats:
//   col i = 3*tl + e
//   shift -24: lane (tl-8)&31,  same elem
//   shift -48: lane (tl-16)&31, same elem
//   shift -72: lane (tl+8)&31,  same elem
//   flip 23-i: lane (7-tl)&31,  elems reversed
//   flip 47-i: lane (15-tl)&31, elems reversed

#define WDIM 96
#define WPB  4               // waves per block (256 threads)
#define NP   9               // row-pairs per wave (18 rows)
#define GRID 2048            // 8 blocks/CU exactly; 2048*4*18 = 147456 rows

typedef float v2f __attribute__((ext_vector_type(2)));

__device__ __forceinline__ float bperm(int byteidx, float v) {
    return __int_as_float(__builtin_amdgcn_ds_bpermute(byteidx, __float_as_int(v)));
}

__global__ __launch_bounds__(64 * WPB)
void symctl_kernel(const float* __restrict__ x,
                   const float* __restrict__ s,
                   const float* __restrict__ w,
                   float* __restrict__ out) {
    const int lane = threadIdx.x & 63;
    const int tl   = lane & 31;          // position within 32-lane half
    const int hsel = lane & 32;          // half selector (0 / 32)
    const int h    = lane >> 5;          // row parity within each pair

    const int gw   = blockIdx.x * WPB + (threadIdx.x >> 6);   // global wave id
    // wave owns rows [18*gw, 18*gw+18); lane covers rows 18*gw + 2k + h
    const int voff = ((18 * gw + h) * WDIM + 3 * tl) * 4;     // byte offset, <2^31

    // ---- gates FIRST (scalar path; fence below pins them above the pipeline) ----
    const int b = blockIdx.x >> 7;       // 2048 blocks / 16 batches = 128
    const float* sb = s + b * 5;
    const float sg0 = 1.0f / (1.0f + __expf(-sb[0]));
    const float sg1 = 1.0f / (1.0f + __expf(-sb[1]));
    const float sg2 = 1.0f / (1.0f + __expf(-sb[2]));
    const float sg3 = 1.0f / (1.0f + __expf(-sb[3]));
    const float sg4 = 1.0f / (1.0f + __expf(-sb[4]));

    // bpermute byte indices (per-lane constants, stay within own 32-lane half)
    const int i90  = (hsel | ((tl -  8) & 31)) << 2;
    const int i180 = (hsel | ((tl - 16) & 31)) << 2;
    const int i270 = (hsel | ((tl +  8) & 31)) << 2;
    const int f90  = (hsel | (( 7 - tl) & 31)) << 2;
    const int f180 = (hsel | ((15 - tl) & 31)) << 2;

    __builtin_amdgcn_sched_barrier(0);   // nothing above (incl. gate loads) may sink below

    // 3 rolling slots (A: pairs 0,3,6; B: 1,4,7; C: 2,5,8)
    v2f   xloA, xloB, xloC, wloA, wloB, wloC;
    float xhiA, xhiB, xhiC, whiA, whiB, whiC;

#define LD(K, XLO, XHI, WLO, WHI)                                               \
    {                                                                           \
        const int a_ = voff + (K) * 768;                                        \
        asm volatile("global_load_dwordx2 %0, %1, %2 nt"                        \
                     : "=v"(XLO) : "v"(a_), "s"(x));                            \
        asm volatile("global_load_dword %0, %1, %2 offset:8 nt"                 \
                     : "=v"(XHI) : "v"(a_), "s"(x));                            \
        asm volatile("global_load_dwordx2 %0, %1, %2 nt"                        \
                     : "=v"(WLO) : "v"(a_), "s"(w));                            \
        asm volatile("global_load_dword %0, %1, %2 offset:8 nt"                 \
                     : "=v"(WHI) : "v"(a_), "s"(w));                            \
    }

#define WAITN(N)                                                                \
    asm volatile("s_waitcnt vmcnt(" #N ")" ::: "memory");                       \
    __builtin_amdgcn_sched_barrier(0);

#define CST(K, XLO, XHI, WLO, WHI)                                              \
    {                                                                           \
        const float wcx = WLO.x, wcy = WLO.y, wcz = WHI;                        \
        const float p0 = XLO.x * wcx;                                           \
        const float p1 = XLO.y * wcy;                                           \
        const float p2 = XHI   * wcz;                                           \
        float n0 = p0, n1 = p1, n2 = p2;                                        \
        float d0 = wcx, d1 = wcy, d2 = wcz;                                     \
        n0 = fmaf(sg0, bperm(i90,  p0),  n0);                                   \
        n1 = fmaf(sg0, bperm(i90,  p1),  n1);                                   \
        n2 = fmaf(sg0, bperm(i90,  p2),  n2);                                   \
        d0 = fmaf(sg0, bperm(i90,  wcx), d0);                                   \
        d1 = fmaf(sg0, bperm(i90,  wcy), d1);                                   \
        d2 = fmaf(sg0, bperm(i90,  wcz), d2);                                   \
        n0 = fmaf(sg1, bperm(i180, p0),  n0);                                   \
        n1 = fmaf(sg1, bperm(i180, p1),  n1);                                   \
        n2 = fmaf(sg1, bperm(i180, p2),  n2);                                   \
        d0 = fmaf(sg1, bperm(i180, wcx), d0);                                   \
        d1 = fmaf(sg1, bperm(i180, wcy), d1);                                   \
        d2 = fmaf(sg1, bperm(i180, wcz), d2);                                   \
        n0 = fmaf(sg2, bperm(i270, p0),  n0);                                   \
        n1 = fmaf(sg2, bperm(i270, p1),  n1);                                   \
        n2 = fmaf(sg2, bperm(i270, p2),  n2);                                   \
        d0 = fmaf(sg2, bperm(i270, wcx), d0);                                   \
        d1 = fmaf(sg2, bperm(i270, wcy), d1);                                   \
        d2 = fmaf(sg2, bperm(i270, wcz), d2);                                   \
        n0 = fmaf(sg3, bperm(f90,  p2),  n0);                                   \
        n1 = fmaf(sg3, bperm(f90,  p1),  n1);                                   \
        n2 = fmaf(sg3, bperm(f90,  p0),  n2);                                   \
        d0 = fmaf(sg3, bperm(f90,  wcz), d0);                                   \
        d1 = fmaf(sg3, bperm(f90,  wcy), d1);                                   \
        d2 = fmaf(sg3, bperm(f90,  wcx), d2);                                   \
        n0 = fmaf(sg4, bperm(f180, p2),  n0);                                   \
        n1 = fmaf(sg4, bperm(f180, p1),  n1);                                   \
        n2 = fmaf(sg4, bperm(f180, p0),  n2);                                   \
        d0 = fmaf(sg4, bperm(f180, wcz), d0);                                   \
        d1 = fmaf(sg4, bperm(f180, wcy), d1);                                   \
        d2 = fmaf(sg4, bperm(f180, wcx), d2);                                   \
        v2f olo;                                                                \
        olo.x = n0 * __builtin_amdgcn_rcpf(d0);                                 \
        olo.y = n1 * __builtin_amdgcn_rcpf(d1);                                 \
        const float ohi = n2 * __builtin_amdgcn_rcpf(d2);                       \
        const int a_ = voff + (K) * 768;                                        \
        asm volatile("global_store_dwordx2 %0, %1, %2 nt"                       \
                     :: "v"(a_), "v"(olo), "s"(out) : "memory");                \
        asm volatile("global_store_dword %0, %1, %2 offset:8 nt"                \
                     :: "v"(a_), "v"(ohi), "s"(out) : "memory");                \
    }

    // ---- prologue: pairs 0,1 in flight ----
    LD(0, xloA, xhiA, wloA, whiA)
    LD(1, xloB, xhiB, wloB, whiB)

    // ---- rolling pipeline, fully static (slots and waits hardcoded) ----
    LD(2, xloC, xhiC, wloC, whiC)  WAITN(8)   CST(0, xloA, xhiA, wloA, whiA)
    LD(3, xloA, xhiA, wloA, whiA)  WAITN(10)  CST(1, xloB, xhiB, wloB, whiB)
    LD(4, xloB, xhiB, wloB, whiB)  WAITN(12)  CST(2, xloC, xhiC, wloC, whiC)
    LD(5, xloC, xhiC, wloC, whiC)  WAITN(12)  CST(3, xloA, xhiA, wloA, whiA)
    LD(6, xloA, xhiA, wloA, whiA)  WAITN(12)  CST(4, xloB, xhiB, wloB, whiB)
    LD(7, xloB, xhiB, wloB, whiB)  WAITN(12)  CST(5, xloC, xhiC, wloC, whiC)
    LD(8, xloC, xhiC, wloC, whiC)  WAITN(12)  CST(6, xloA, xhiA, wloA, whiA)
                                   WAITN(8)   CST(7, xloB, xhiB, wloB, whiB)
                                   WAITN(4)   CST(8, xloC, xhiC, wloC, whiC)

#undef LD
#undef WAITN
#undef CST
}

extern "C" void kernel_launch(void* const* d_in, const int* in_sizes, int n_in,
                              void* d_out, int out_size, void* d_ws, size_t ws_size,
                              hipStream_t stream) {
    const float* x = (const float*)d_in[0];
    const float* s = (const float*)d_in[1];
    const float* w = (const float*)d_in[2];
    float* out = (float*)d_out;

    // 2048 blocks x 4 waves x 18 rows = 147456 rows (exact for the fixed shape)
    dim3 block(64 * WPB);
    symctl_kernel<<<GRID, block, 0, stream>>>(x, s, w, out);
}